// Round 7
// baseline (820.925 us; speedup 1.0000x reference)
//
#include <hip/hip_runtime.h>
#include <math.h>

#define S_   4096
#define H_   8
#define HD_  512
#define NCH  256   // chunks per batch
#define LCH  16    // seq steps per chunk

typedef __bf16 bf16x8 __attribute__((ext_vector_type(8)));
typedef float  f32x4  __attribute__((ext_vector_type(4)));

__device__ __forceinline__ float sigm(float v) { return 1.f / (1.f + __expf(-v)); }

// XOR-swizzled element index within a 128-bf16 row (16 groups of 8).
__device__ __forceinline__ int swz(int row, int k) {
  return ((((k >> 3) ^ (row & 15)) << 3) | (k & 7));
}

// Manual grid barrier (plain kernel => graph-capture safe).
// Monotonic counter; phase P waits for 512*P. Counter zeroed by k_init.
// Co-residency: 64 KiB LDS -> exactly 2 blocks/CU, grid=512=2*256 CUs.
__device__ __forceinline__ void gridbar(int* bar, int target) {
  __threadfence();
  __syncthreads();
  if (threadIdx.x == 0) {
    __hip_atomic_fetch_add(bar, 1, __ATOMIC_RELEASE, __HIP_MEMORY_SCOPE_AGENT);
    int v;
    do {
      v = __hip_atomic_load(bar, __ATOMIC_ACQUIRE, __HIP_MEMORY_SCOPE_AGENT);
      if (v < target) __builtin_amdgcn_s_sleep(4);
    } while (v < target);
  }
  __syncthreads();
  __threadfence();
}

__global__ void k_init(int* bar) { *bar = 0; }

__global__ __launch_bounds__(256, 2) void k_fused(
    const float* __restrict__ x, const float* __restrict__ Wh,
    const float* __restrict__ bh, const float* __restrict__ Wo,
    const float* __restrict__ bo, const float* __restrict__ gamma,
    const float* __restrict__ beta, const float* __restrict__ initcx,
    float* __restrict__ out,
    float* __restrict__ sums, float* __restrict__ offs,
    float* __restrict__ cA, float* __restrict__ cB, float* __restrict__ cin,
    __bf16* __restrict__ WthS, __bf16* __restrict__ WtoS, int* bar) {
  __shared__ __bf16 At[2 * 128 * 128];   // 65536 B exactly
  const int t = threadIdx.x, blk = blockIdx.x;
  const int wave = t >> 6, lane = t & 63;
  const int quad = lane >> 4, l16 = lane & 15;

  // ===== phase A: x -> bf16 LDS tiles + chunk sums; weight swizzle ==========
  #pragma unroll
  for (int cc = 0; cc < 2; ++cc) {
    int g = blk * 2 + cc, b = g >> 8, c = g & 255;
    int hd0 = t * 2, h = hd0 >> 6, d0 = hd0 & 63;
    const float2* xp = (const float2*)(x + ((size_t)(b * S_ + c * LCH)) * HD_) + t;
    float a0 = 0.f, a1 = 0.f;
    #pragma unroll
    for (int s = 0; s < LCH; ++s) {
      float2 v = xp[s * 256];
      a0 += v.x; a1 += v.y;
      int row = h * LCH + s;
      __bf16* base = &At[cc * 16384 + row * 128];
      base[swz(row, d0)]     = (__bf16)v.x;
      base[swz(row, d0 + 1)] = (__bf16)v.y;
    }
    ((float2*)(sums + (size_t)g * HD_))[t] = make_float2(a0, a1);
  }
  if (blk < 128) {
    int idx = blk * 256 + t;
    if (idx < 24576) {
      int k = idx / 192, n = idx % 192;
      int nt = n >> 4, j16 = n & 15;
      int ks = k >> 5, q = (k >> 3) & 3, j = k & 7;
      WthS[(((ks * 12 + nt) * 64) + q * 16 + j16) * 8 + j] = (__bf16)Wh[idx];
    } else {
      int j2 = idx - 24576, k = j2 >> 6, n = j2 & 63;
      int nt = n >> 4, j16 = n & 15;
      int ks = k >> 5, q = (k >> 3) & 3, j = k & 7;
      WtoS[(((ks * 4 + nt) * 64) + q * 16 + j16) * 8 + j] = (__bf16)Wo[j2];
    }
  }
  gridbar(bar, 512);

  // ===== phase B: exclusive scan of chunk sums ==============================
  if (blk < 8) {
    int batch = blk >> 1, half = blk & 1, hd = half * 256 + t;
    float run = 0.f;
    #pragma unroll 8
    for (int c = 0; c < NCH; ++c) {
      size_t idx = ((size_t)batch * NCH + c) * HD_ + hd;
      float v = sums[idx];
      offs[idx] = run;
      run += v;
    }
  }
  gridbar(bar, 1024);

  // ===== phase C: barrier-free LN into LDS + gates GEMM -> (cA, cB) =========
  float ga[8], be8[8];
  #pragma unroll
  for (int h = 0; h < 8; ++h) { ga[h] = gamma[h * 64 + lane]; be8[h] = beta[h * 64 + lane]; }

  #pragma unroll 1
  for (int cc = 0; cc < 2; ++cc) {
    int g = blk * 2 + cc;
    {  // wave-redundant LN: lane owns d=lane, keeps run[h] for all 8 heads
      float run[8];
      #pragma unroll
      for (int h = 0; h < 8; ++h) run[h] = offs[(size_t)g * HD_ + h * 64 + lane];
      for (int s = 0; s < LCH; ++s) {
        float xv[8], p1 = 0.f, p2 = 0.f;
        #pragma unroll
        for (int h = 0; h < 8; ++h) {
          int row = h * 16 + s;
          xv[h] = (float)At[cc * 16384 + row * 128 + swz(row, lane)];
          p1 += run[h];
          p2 += run[h] * run[h];
        }
        #pragma unroll
        for (int o = 32; o; o >>= 1) { p1 += __shfl_xor(p1, o); p2 += __shfl_xor(p2, o); }
        float m = p1 * (1.f / HD_);
        float var = fmaf(-m, m, p2 * (1.f / HD_));
        float inv = rsqrtf(var + 1e-5f);
        #pragma unroll
        for (int hh = 0; hh < 2; ++hh) {
          int h = wave * 2 + hh, row = h * 16 + s;
          At[cc * 16384 + row * 128 + swz(row, 64 + lane)] =
              (__bf16)((run[h] - m) * inv * ga[h] + be8[h]);
        }
        #pragma unroll
        for (int h = 0; h < 8; ++h) run[h] += xv[h];
      }
    }
    __syncthreads();

    f32x4 acc[2][12];
    #pragma unroll
    for (int i = 0; i < 2; ++i)
      #pragma unroll
      for (int j = 0; j < 12; ++j) acc[i][j] = (f32x4){0.f, 0.f, 0.f, 0.f};
    #pragma unroll
    for (int ks = 0; ks < 4; ++ks) {
      bf16x8 bfrag[12];
      #pragma unroll
      for (int nt = 0; nt < 12; ++nt)
        bfrag[nt] = *(const bf16x8*)(WthS + (size_t)((ks * 12 + nt) * 64 + lane) * 8);
      #pragma unroll
      for (int mi = 0; mi < 2; ++mi) {
        int h = wave * 2 + mi, row = h * 16 + l16;
        int pg = (ks * 4 + quad) ^ (row & 15);
        bf16x8 afrag = *(const bf16x8*)&At[cc * 16384 + row * 128 + pg * 8];
        #pragma unroll
        for (int nt = 0; nt < 12; ++nt)
          acc[mi][nt] = __builtin_amdgcn_mfma_f32_16x16x32_bf16(afrag, bfrag[nt], acc[mi][nt], 0, 0, 0);
      }
    }
    #pragma unroll
    for (int mi = 0; mi < 2; ++mi) {
      int h = wave * 2 + mi;
      #pragma unroll
      for (int nt = 0; nt < 4; ++nt) {
        int d = nt * 16 + l16;
        float bi = bh[d], bf = bh[64 + d], bhv = bh[128 + d];
        float A = 1.f, Bv = 0.f;
        #pragma unroll
        for (int r = 0; r < 4; ++r) {
          float f = sigm(acc[mi][nt + 4][r] + bf);
          float gg = sigm(acc[mi][nt][r] + bi) * fmaxf(acc[mi][nt + 8][r] + bhv, 0.f);
          A = f * A;
          Bv = fmaf(f, Bv, gg);
        }
        float Atot = 0.f, Btot = 0.f;
        #pragma unroll
        for (int q = 0; q < 4; ++q) {
          float Aq = __shfl(A, q * 16 + l16);
          float Bq = __shfl(Bv, q * 16 + l16);
          if (q == 0) { Atot = Aq; Btot = Bq; }
          else { Atot = Aq * Atot; Btot = fmaf(Aq, Btot, Bq); }
        }
        if (quad == 0) {
          cA[(size_t)g * HD_ + h * 64 + d] = Atot;
          cB[(size_t)g * HD_ + h * 64 + d] = Btot;
        }
      }
    }
    __syncthreads();
  }
  gridbar(bar, 1536);

  // ===== phase D: cross-chunk cell scan -> cin ==============================
  if (blk < 8) {
    int batch = blk >> 1, half = blk & 1, hd = half * 256 + t;
    float run = initcx[hd];
    #pragma unroll 8
    for (int c = 0; c < NCH; ++c) {
      size_t idx = ((size_t)batch * NCH + c) * HD_ + hd;
      float a = cA[idx], bb = cB[idx];
      cin[idx] = run;
      run = fmaf(a, run, bb);
    }
  }
  gridbar(bar, 2048);

  // ===== phase E: gates recompute + in-reg scan + og GEMM + out=og*cell =====
  #pragma unroll 1
  for (int cc = 0; cc < 2; ++cc) {
    int g = blk * 2 + cc, b = g >> 8, c = g & 255;
    f32x4 acc[2][12];
    #pragma unroll
    for (int i = 0; i < 2; ++i)
      #pragma unroll
      for (int j = 0; j < 12; ++j) acc[i][j] = (f32x4){0.f, 0.f, 0.f, 0.f};
    #pragma unroll
    for (int ks = 0; ks < 4; ++ks) {
      bf16x8 bfrag[12];
      #pragma unroll
      for (int nt = 0; nt < 12; ++nt)
        bfrag[nt] = *(const bf16x8*)(WthS + (size_t)((ks * 12 + nt) * 64 + lane) * 8);
      #pragma unroll
      for (int mi = 0; mi < 2; ++mi) {
        int h = wave * 2 + mi, row = h * 16 + l16;
        int pg = (ks * 4 + quad) ^ (row & 15);
        bf16x8 afrag = *(const bf16x8*)&At[cc * 16384 + row * 128 + pg * 8];
        #pragma unroll
        for (int nt = 0; nt < 12; ++nt)
          acc[mi][nt] = __builtin_amdgcn_mfma_f32_16x16x32_bf16(afrag, bfrag[nt], acc[mi][nt], 0, 0, 0);
      }
    }
    float cellreg[2][4][4];
    #pragma unroll
    for (int mi = 0; mi < 2; ++mi) {
      int h = wave * 2 + mi;
      #pragma unroll
      for (int nt = 0; nt < 4; ++nt) {
        int d = nt * 16 + l16;
        float bi = bh[d], bf = bh[64 + d], bhv = bh[128 + d];
        float fr[4], gr[4];
        float A = 1.f, Bv = 0.f;
        #pragma unroll
        for (int r = 0; r < 4; ++r) {
          fr[r] = sigm(acc[mi][nt + 4][r] + bf);
          gr[r] = sigm(acc[mi][nt][r] + bi) * fmaxf(acc[mi][nt + 8][r] + bhv, 0.f);
          A = fr[r] * A;
          Bv = fmaf(fr[r], Bv, gr[r]);
        }
        float cv = cin[(size_t)g * HD_ + h * 64 + d];
        #pragma unroll
        for (int q = 0; q < 3; ++q) {
          float Aq = __shfl(A, q * 16 + l16);
          float Bq = __shfl(Bv, q * 16 + l16);
          if (q < quad) cv = fmaf(Aq, cv, Bq);
        }
        #pragma unroll
        for (int r = 0; r < 4; ++r) {
          cv = fmaf(fr[r], cv, gr[r]);
          cellreg[mi][nt][r] = cv;
          int row = h * 16 + quad * 4 + r;
          At[cc * 16384 + row * 128 + swz(row, 64 + d)] = (__bf16)cv;
        }
      }
    }
    f32x4 acc2[2][4];
    #pragma unroll
    for (int i = 0; i < 2; ++i)
      #pragma unroll
      for (int j = 0; j < 4; ++j) acc2[i][j] = (f32x4){0.f, 0.f, 0.f, 0.f};
    #pragma unroll
    for (int ks = 0; ks < 4; ++ks) {
      bf16x8 bfrag[4];
      #pragma unroll
      for (int nt = 0; nt < 4; ++nt)
        bfrag[nt] = *(const bf16x8*)(WtoS + (size_t)((ks * 4 + nt) * 64 + lane) * 8);
      #pragma unroll
      for (int mi = 0; mi < 2; ++mi) {
        int h = wave * 2 + mi, row = h * 16 + l16;
        int pg = (ks * 4 + quad) ^ (row & 15);
        bf16x8 afrag = *(const bf16x8*)&At[cc * 16384 + row * 128 + pg * 8];
        #pragma unroll
        for (int nt = 0; nt < 4; ++nt)
          acc2[mi][nt] = __builtin_amdgcn_mfma_f32_16x16x32_bf16(afrag, bfrag[nt], acc2[mi][nt], 0, 0, 0);
      }
    }
    #pragma unroll
    for (int mi = 0; mi < 2; ++mi) {
      int h = wave * 2 + mi;
      #pragma unroll
      for (int nt = 0; nt < 4; ++nt) {
        int d = nt * 16 + l16;
        float bv = bo[d];
        #pragma unroll
        for (int r = 0; r < 4; ++r) {
          int s = quad * 4 + r;
          float og = sigm(acc2[mi][nt][r] + bv);
          out[((size_t)((b * S_ + c * LCH + s) * H_ + h)) * 64 + d] = og * cellreg[mi][nt][r];
        }
      }
    }
    __syncthreads();
  }
}

extern "C" void kernel_launch(void* const* d_in, const int* in_sizes, int n_in,
                              void* d_out, int out_size, void* d_ws, size_t ws_size,
                              hipStream_t stream) {
  const float* x      = (const float*)d_in[0];
  const float* W_hid  = (const float*)d_in[1];
  const float* b_hid  = (const float*)d_in[2];
  const float* W_og   = (const float*)d_in[3];
  const float* b_og   = (const float*)d_in[4];
  const float* gamma  = (const float*)d_in[5];
  const float* beta   = (const float*)d_in[6];
  const float* initcx = (const float*)d_in[7];
  float* out = (float*)d_out;
  float* ws  = (float*)d_ws;

  const size_t SM = 524288;  // 1024 chunks x 512 floats (2 MB each)
  int*    bar  = (int*)ws;                   // 64 B reserved
  float*  sums = ws + 16;
  float*  offs = sums + SM;
  float*  cAp  = offs + SM;
  float*  cBp  = cAp + SM;
  float*  cinp = cBp + SM;
  __bf16* WthS = (__bf16*)(cinp + SM);
  __bf16* WtoS = WthS + 24576;

  k_init<<<1, 1, 0, stream>>>(bar);
  k_fused<<<512, 256, 0, stream>>>(x, W_hid, b_hid, W_og, b_og, gamma, beta,
                                   initcx, out, sums, offs, cAp, cBp, cinp,
                                   WthS, WtoS, bar);
}